// Round 19
// baseline (418.917 us; speedup 1.0000x reference)
//
#include <hip/hip_runtime.h>
#include <hip/hip_bf16.h>

#define K_DIM 512
#define N_DIM 512

typedef __attribute__((ext_vector_type(8))) short s8v;   // 8 bf16 bit-patterns (4 VGPR)
typedef __attribute__((ext_vector_type(4))) short s4v;
typedef __attribute__((ext_vector_type(4))) float f4v;

__device__ __forceinline__ short f2bf(float f) {
  union { float f; unsigned u; } v; v.f = f;
  unsigned r = (v.u + 0x7FFFu + ((v.u >> 16) & 1u)) >> 16;  // RNE
  return (short)r;
}
__device__ __forceinline__ float bflo(unsigned u) {
  union { unsigned u; float f; } v; v.u = u << 16; return v.f;
}
__device__ __forceinline__ float bfhi(unsigned u) {
  union { unsigned u; float f; } v; v.u = u & 0xffff0000u; return v.f;
}

// async global->LDS, 16B per lane. LDS dest = wave-uniform base (HW adds lane*16);
// global src is per-lane.
__device__ __forceinline__ void gload16(const void* g, void* l) {
  __builtin_amdgcn_global_load_lds(
      (const __attribute__((address_space(1))) void*)g,
      (__attribute__((address_space(3))) void*)l, 16, 0, 0);
}

// Per-wave inline int64-vs-int32 detection for edge_index (odd words all zero
// over the first 64 slots <=> int64 layout).
__device__ __forceinline__ int edge_stride(const int* __restrict__ e32, int lane) {
  int chk = e32[2 * lane + 1];
  unsigned long long m = __ballot(chk == 0);
  return (m == ~0ULL) ? 2 : 1;
}

// ===== PROBE KERNELS (measurement only; outputs unused / overwritten) =====

// 4x replica of the convX section: cost/4 = true convX time.
__global__ __launch_bounds__(256) void k_probe_conv(const float* __restrict__ x,
    short* __restrict__ xd, long long n4) {
  const float4* x4 = (const float4*)x;
  s4v* xd4 = (s4v*)xd;
  const long long stride = (long long)gridDim.x * 256;
  for (int rep = 0; rep < 4; ++rep) {
    for (long long i = (long long)blockIdx.x * 256 + threadIdx.x; i < n4;
         i += 4 * stride) {
      float4 f[4];
      #pragma unroll
      for (int u = 0; u < 4; ++u) {
        long long j = i + u * stride;
        f[u] = (j < n4) ? x4[j] : float4{0.f, 0.f, 0.f, 0.f};
      }
      #pragma unroll
      for (int u = 0; u < 4; ++u) {
        long long j = i + u * stride;
        if (j < n4) {
          s4v s;
          s[0] = f2bf(f[u].x); s[1] = f2bf(f[u].y);
          s[2] = f2bf(f[u].z); s[3] = f2bf(f[u].w);
          xd4[j] = s;
        }
      }
    }
  }
}

// 4x replica of the hist section's atomics into dummy arrays: cost/4 ~ hist time.
__global__ __launch_bounds__(256) void k_probe_hist(const int* __restrict__ e32,
    int* __restrict__ outd, int* __restrict__ ind, int E) {
  int t = threadIdx.x;
  int st = edge_stride(e32, t & 63);
  int i = blockIdx.x * 256 + t;
  if (i < E) {
    int r = e32[(size_t)i * st];
    int c = e32[(size_t)(E + i) * st];
    #pragma unroll
    for (int rep = 0; rep < 4; ++rep) {
      atomicAdd(&outd[r], 1);
      atomicAdd(&ind[c], 1);
    }
  }
}

// ===== R16 pipeline (best known config, byte-identical) =====

// Fused prep: [0,nbw) convW | [nbw,nbw+nbx) convX grid-stride ILP-4 | rest hist.
__global__ __launch_bounds__(256) void k_pre1(const float* __restrict__ W,
    short* __restrict__ Wb, const float* __restrict__ x, short* __restrict__ xs,
    long long n4, const int* __restrict__ e32,
    int* __restrict__ outdeg, int* __restrict__ indeg, int E, int nbw, int nbx) {
  int b = blockIdx.x;
  int t = threadIdx.x;
  if (b < nbw) {
    int i = (b * 256 + t) * 4;
    float4 f = *(const float4*)(W + i);
    s4v s; s[0] = f2bf(f.x); s[1] = f2bf(f.y); s[2] = f2bf(f.z); s[3] = f2bf(f.w);
    *(s4v*)(Wb + i) = s;
  } else if (b < nbw + nbx) {
    const float4* x4 = (const float4*)x;
    s4v* xs4 = (s4v*)xs;
    long long i0 = (long long)(b - nbw) * 256 + t;
    const long long stride = (long long)nbx * 256;
    for (long long i = i0; i < n4; i += 4 * stride) {
      float4 f[4];
      #pragma unroll
      for (int u = 0; u < 4; ++u) {
        long long j = i + u * stride;
        f[u] = (j < n4) ? x4[j] : float4{0.f, 0.f, 0.f, 0.f};
      }
      #pragma unroll
      for (int u = 0; u < 4; ++u) {
        long long j = i + u * stride;
        if (j < n4) {
          s4v s;
          s[0] = f2bf(f[u].x); s[1] = f2bf(f[u].y);
          s[2] = f2bf(f[u].z); s[3] = f2bf(f[u].w);
          xs4[j] = s;
        }
      }
    }
  } else {
    int st = edge_stride(e32, t & 63);
    int i = (b - nbw - nbx) * 256 + t;
    if (i < E) {
      int r = e32[(size_t)i * st];
      int c = e32[(size_t)(E + i) * st];
      atomicAdd(&outdeg[r], 1);
      atomicAdd(&indeg[c], 1);
    }
  }
}

// Fused: [0,nbd) dis | [nbd,..) per-block partial sums of indeg.
__global__ __launch_bounds__(256) void k_pre2(const int* __restrict__ outdeg,
    float* __restrict__ dis, const int* __restrict__ indeg, int* __restrict__ part,
    int n, int nbd) {
  int b = blockIdx.x;
  if (b < nbd) {
    int i = b * 256 + threadIdx.x;
    if (i < n) dis[i] = rsqrtf((float)(outdeg[i] + 1));  // +1 self-loop
  } else {
    __shared__ int sm[256];
    int lb = b - nbd;
    int i = lb * 256 + threadIdx.x;
    sm[threadIdx.x] = (i < n) ? indeg[i] : 0;
    __syncthreads();
    for (int off = 128; off > 0; off >>= 1) {
      if (threadIdx.x < off) sm[threadIdx.x] += sm[threadIdx.x + off];
      __syncthreads();
    }
    if (threadIdx.x == 0) part[lb] = sm[0];
  }
}

// Self-contained scan: re-scan the <=256 PARTIALS in LDS, then local-scan slice.
__global__ __launch_bounds__(256) void k_scan(const int* __restrict__ indeg,
    const int* __restrict__ part, int* __restrict__ row_start,
    int* __restrict__ cursor, int n, int nb) {
  __shared__ int sp[256];
  __shared__ int sm[256];
  int t = threadIdx.x, b = blockIdx.x;
  sp[t] = (t < nb) ? part[t] : 0;
  __syncthreads();
  for (int off = 1; off < 256; off <<= 1) {
    int a = (t >= off) ? sp[t - off] : 0;
    __syncthreads();
    sp[t] += a;
    __syncthreads();
  }
  int pOff = (b > 0) ? sp[b - 1] : 0;
  if (b == 0 && t == 255) row_start[n] = sp[255];  // grand total (= E)
  int i = b * 256 + t;
  int v = (i < n) ? indeg[i] : 0;
  sm[t] = v;
  __syncthreads();
  for (int off = 1; off < 256; off <<= 1) {
    int a = (t >= off) ? sm[t - off] : 0;
    __syncthreads();
    sm[t] += a;
    __syncthreads();
  }
  if (i < n) {
    int excl = pOff + sm[t] - v;
    row_start[i] = excl;
    cursor[i] = excl;
  }
}

__global__ __launch_bounds__(256) void k_fill(const int* __restrict__ e32,
    int* __restrict__ cursor, int* __restrict__ csr, int E) {
  int st = edge_stride(e32, threadIdx.x & 63);
  int i = blockIdx.x * blockDim.x + threadIdx.x;
  if (i >= E) return;
  int r = e32[(size_t)i * st];
  int c = e32[(size_t)(E + i) * st];
  int p = atomicAdd(&cursor[c], 1);
  csr[p] = r;
}

__device__ __forceinline__ void fma4(float* acc, uint2 rv, float w) {
  acc[0] += w * bflo(rv.x); acc[1] += w * bfhi(rv.x);
  acc[2] += w * bflo(rv.y); acc[3] += w * bfhi(rv.y);
}

// Column-half aggregation pass: gathers only cols [coff, coff+256).
__global__ __launch_bounds__(256) void k_agg(const short* __restrict__ xs,
    const float* __restrict__ dis, const int* __restrict__ row_start,
    const int* __restrict__ csr, short* __restrict__ xa, float* __restrict__ s,
    int n, int coff, int writeS) {
  int wid = blockIdx.x * 4 + (threadIdx.x >> 6);
  int nw = gridDim.x * 4;
  int lane = threadIdx.x & 63;
  const short* hl = xs + coff + lane * 4;   // 8B per lane, 512B per row slice
  for (int v = wid; v < n; v += nw) {
    float dv = dis[v];
    float acc[4];
    float accs = dv;
    {
      uint2 r = *(const uint2*)(hl + (size_t)v * N_DIM);  // self-loop (w = dv)
      acc[0] = dv * bflo(r.x); acc[1] = dv * bfhi(r.x);
      acc[2] = dv * bflo(r.y); acc[3] = dv * bfhi(r.y);
    }
    int sb = __builtin_amdgcn_readfirstlane(row_start[v]);
    int eb = __builtin_amdgcn_readfirstlane(row_start[v + 1]);
    int idx = sb;
    for (; idx + 8 <= eb; idx += 8) {
      int s0 = csr[idx],     s1 = csr[idx + 1], s2 = csr[idx + 2], s3 = csr[idx + 3];
      int s4 = csr[idx + 4], s5 = csr[idx + 5], s6 = csr[idx + 6], s7 = csr[idx + 7];
      float w0 = dis[s0], w1 = dis[s1], w2 = dis[s2], w3 = dis[s3];
      float w4 = dis[s4], w5 = dis[s5], w6 = dis[s6], w7 = dis[s7];
      uint2 r0 = *(const uint2*)(hl + (size_t)s0 * N_DIM);
      uint2 r1 = *(const uint2*)(hl + (size_t)s1 * N_DIM);
      uint2 r2 = *(const uint2*)(hl + (size_t)s2 * N_DIM);
      uint2 r3 = *(const uint2*)(hl + (size_t)s3 * N_DIM);
      uint2 r4 = *(const uint2*)(hl + (size_t)s4 * N_DIM);
      uint2 r5 = *(const uint2*)(hl + (size_t)s5 * N_DIM);
      uint2 r6 = *(const uint2*)(hl + (size_t)s6 * N_DIM);
      uint2 r7 = *(const uint2*)(hl + (size_t)s7 * N_DIM);
      accs += w0 + w1 + w2 + w3 + w4 + w5 + w6 + w7;
      fma4(acc, r0, w0); fma4(acc, r1, w1); fma4(acc, r2, w2); fma4(acc, r3, w3);
      fma4(acc, r4, w4); fma4(acc, r5, w5); fma4(acc, r6, w6); fma4(acc, r7, w7);
    }
    for (; idx + 4 <= eb; idx += 4) {
      int s0 = csr[idx], s1 = csr[idx + 1], s2 = csr[idx + 2], s3 = csr[idx + 3];
      float w0 = dis[s0], w1 = dis[s1], w2 = dis[s2], w3 = dis[s3];
      uint2 r0 = *(const uint2*)(hl + (size_t)s0 * N_DIM);
      uint2 r1 = *(const uint2*)(hl + (size_t)s1 * N_DIM);
      uint2 r2 = *(const uint2*)(hl + (size_t)s2 * N_DIM);
      uint2 r3 = *(const uint2*)(hl + (size_t)s3 * N_DIM);
      accs += w0 + w1 + w2 + w3;
      fma4(acc, r0, w0); fma4(acc, r1, w1); fma4(acc, r2, w2); fma4(acc, r3, w3);
    }
    for (; idx < eb; ++idx) {
      int s0 = csr[idx];
      float w0 = dis[s0];
      uint2 r0 = *(const uint2*)(hl + (size_t)s0 * N_DIM);
      accs += w0;
      fma4(acc, r0, w0);
    }
    s4v o;
    o[0] = f2bf(dv * acc[0]); o[1] = f2bf(dv * acc[1]);
    o[2] = f2bf(dv * acc[2]); o[3] = f2bf(dv * acc[3]);
    *(s4v*)(xa + (size_t)v * N_DIM + coff + lane * 4) = o;
    if (writeS && lane == 0) s[v] = dv * accs;
  }
}

// out[M][512] (f32) = relu( xa[M][512](bf16) @ Wb^T + s[row]*bias )
// R10-proven: m97-lean 2-phase K-loop + LDS-transpose epilogue.
__global__ __launch_bounds__(256, 4) void k_gemm(const short* __restrict__ xa,
    const short* __restrict__ Wb, const float* __restrict__ bias,
    const float* __restrict__ s, float* __restrict__ out, int M) {
  __shared__ __align__(16) char smem[32768];
  short* As = (short*)smem;             // [2][128*32] shorts = 16KB
  short* Bs = (short*)(smem + 16384);   // 16KB
  // --- XCD-chunked bijective swizzle (8 XCDs, m204) ---
  int nwg = gridDim.x;
  int orig = blockIdx.x;
  int q8 = nwg >> 3, r8 = nwg & 7;
  int xcd = orig & 7, pos = orig >> 3;
  int swz = (xcd < r8 ? xcd * (q8 + 1) : r8 * (q8 + 1) + (xcd - r8) * q8) + pos;
  const int n0 = (swz & 3) * 128;    // N fastest within swz chunk
  const int m0 = (swz >> 2) * 128;

  const int tid = threadIdx.x;
  const int lane = tid & 63;
  const int wv = tid >> 6, wr = wv >> 1, wc = wv & 1;
  const int la = lane & 15, lg = lane >> 4;

  // staging: 2 rounds x 256 lanes x 16B cover 128 rows x 64B (BK=32 bf16)
  const short* ag[2];
  const short* bg[2];
  int doff[2];
  #pragma unroll
  for (int r = 0; r < 2; ++r) {
    int id = r * 256 + tid;
    int row = id >> 2;               // 0..127
    int ch = id & 3;                 // 16B chunk within row
    int arow = m0 + row; if (arow >= M) arow = M - 1;  // clamp: no OOB
    ag[r] = xa + (size_t)arow * K_DIM + ch * 8;
    bg[r] = Wb + (size_t)(n0 + row) * K_DIM + ch * 8;
    doff[r] = (r * 256 + (tid & 192)) * 16;  // wave-uniform byte base
  }
  // fragment read offsets
  int aro[4], bro[4];
  #pragma unroll
  for (int i = 0; i < 4; ++i) {
    aro[i] = (64 * wr + 16 * i + la) * 64 + lg * 16;
    bro[i] = (64 * wc + 16 * i + la) * 64 + lg * 16;
  }

  f4v acc[4][4] = {};

  // prologue: k-tile 0 -> buffer 0
  #pragma unroll
  for (int r = 0; r < 2; ++r) {
    gload16(ag[r], (char*)As + doff[r]);
    gload16(bg[r], (char*)Bs + doff[r]);
  }
  __syncthreads();

  for (int kt = 0; kt < 16; ++kt) {
    const int cur = kt & 1;
    const int nxt = cur ^ 1;
    if (kt < 15) {
      const int kk = (kt + 1) * 32;
      #pragma unroll
      for (int r = 0; r < 2; ++r) {
        gload16(ag[r] + kk, (char*)As + nxt * 8192 + doff[r]);
        gload16(bg[r] + kk, (char*)Bs + nxt * 8192 + doff[r]);
      }
    }
    s8v af[4], bf[4];
    const char* ab = (const char*)As + cur * 8192;
    const char* bb = (const char*)Bs + cur * 8192;
    #pragma unroll
    for (int i = 0; i < 4; ++i) af[i] = *(const s8v*)(ab + aro[i]);
    #pragma unroll
    for (int j = 0; j < 4; ++j) bf[j] = *(const s8v*)(bb + bro[j]);
    #pragma unroll
    for (int i = 0; i < 4; ++i)
      #pragma unroll
      for (int j = 0; j < 4; ++j)
        acc[i][j] = __builtin_amdgcn_mfma_f32_16x16x32_bf16(af[i], bf[j], acc[i][j], 0, 0, 0);
    __syncthreads();  // drains vmcnt/lgkm: nxt staged, cur reads done
  }

  // epilogue: per 16-row slice, transpose through per-wave LDS region.
  float* Es = (float*)(smem + wv * 4352);
  float bv[4];
  #pragma unroll
  for (int j = 0; j < 4; ++j) bv[j] = bias[n0 + 64 * wc + 16 * j + la];
  #pragma unroll
  for (int i = 0; i < 4; ++i) {
    int rowb = m0 + 64 * wr + 16 * i + lg * 4;
    float sv[4];
    #pragma unroll
    for (int r = 0; r < 4; ++r) sv[r] = (rowb + r < M) ? s[rowb + r] : 0.f;
    #pragma unroll
    for (int j = 0; j < 4; ++j)
      #pragma unroll
      for (int r = 0; r < 4; ++r)
        Es[(lg * 4 + r) * 68 + 16 * j + la] = fmaxf(acc[i][j][r] + sv[r] * bv[j], 0.f);
    asm volatile("s_waitcnt lgkmcnt(0)" ::: "memory");  // ds_writes visible
    int gr0 = m0 + 64 * wr + 16 * i;
    #pragma unroll
    for (int rr = 0; rr < 4; ++rr) {
      int id = rr * 64 + lane;
      int rl = id >> 4, ch = id & 15;
      f4v val = *(const f4v*)&Es[rl * 68 + ch * 4];
      if (gr0 + rl < M)
        __builtin_nontemporal_store(val,
            (f4v*)(out + (size_t)(gr0 + rl) * N_DIM + n0 + 64 * wc + ch * 4));
    }
    asm volatile("s_waitcnt lgkmcnt(0)" ::: "memory");  // reads done before next i
  }
}

extern "C" void kernel_launch(void* const* d_in, const int* in_sizes, int n_in,
                              void* d_out, int out_size, void* d_ws, size_t ws_size,
                              hipStream_t stream) {
  const float* x = (const float*)d_in[0];
  const int* e32 = (const int*)d_in[1];
  const float* W = (const float*)d_in[2];
  const float* bias = (const float*)d_in[3];
  float* out = (float*)d_out;
  int M = in_sizes[0] / K_DIM;   // 50000
  int E = in_sizes[1] / 2;       // 400000

  char* ws = (char*)d_ws;
  size_t off = 0;
  auto alloc = [&](size_t bytes) {
    void* p = ws + off;
    off = (off + bytes + 255) & ~(size_t)255;
    return p;
  };
  short* Wb      = (short*)alloc((size_t)N_DIM * K_DIM * 2);
  short* xa      = (short*)alloc((size_t)M * N_DIM * 2);   // aggregated bf16 features
  float* dis     = (float*)alloc((size_t)M * 4);
  float* sv      = (float*)alloc((size_t)M * 4);           // s[v] bias scale
  int*   outdeg  = (int*)alloc((size_t)M * 4);
  int*   indeg   = (int*)alloc((size_t)M * 4);             // contiguous after outdeg
  int*   rstart  = (int*)alloc((size_t)(M + 1) * 4);
  int*   cursor  = (int*)alloc((size_t)M * 4);
  int*   part    = (int*)alloc(256 * 4);
  int*   csr     = (int*)alloc((size_t)E * 4);
  int*   degd1   = (int*)alloc((size_t)M * 4);             // probe dummies
  int*   degd2   = (int*)alloc((size_t)M * 4);
  if (off > ws_size) return;  // workspace too small: fail loudly via absmax

  // xs (plain bf16 x) lives in d_out's first half; probe conv writes 2nd half.
  short* xs = (short*)d_out;                       // 51.2MB
  short* xd = (short*)d_out + (size_t)M * K_DIM;   // dummy 51.2MB (out overwrites)

  // one memset covers outdeg..indeg (contiguous in ws)
  size_t zbytes = (size_t)((char*)indeg - (char*)outdeg) + (size_t)M * 4;
  (void)hipMemsetAsync(outdeg, 0, zbytes, stream);

  long long n4 = (long long)M * K_DIM / 4;            // 6.4M float4s
  int nbw = N_DIM * K_DIM / 4 / 256;                  // 256
  int nbx = 2048;                                     // grid-stride convX blocks
  int nbh = (E + 255) / 256;                          // 1563

  // ---- probes (outputs unused; timing only) ----
  k_probe_conv<<<2048, 256, 0, stream>>>(x, xd, n4);
  k_probe_hist<<<nbh, 256, 0, stream>>>(e32, degd1, degd2, E);

  // ---- real pipeline (R16, best) ----
  k_pre1<<<nbw + nbx + nbh, 256, 0, stream>>>(W, Wb, x, xs, n4, e32,
                                              outdeg, indeg, E, nbw, nbx);
  int nscan = (M + 255) / 256;  // 196 (must be <= 256)
  k_pre2<<<nscan * 2, 256, 0, stream>>>(outdeg, dis, indeg, part, M, nscan);
  k_scan<<<nscan, 256, 0, stream>>>(indeg, part, rstart, cursor, M, nscan);
  k_fill<<<nbh, 256, 0, stream>>>(e32, cursor, csr, E);
  k_agg<<<2048, 256, 0, stream>>>(xs, dis, rstart, csr, xa, sv, M, 0, 1);
  k_agg<<<2048, 256, 0, stream>>>(xs, dis, rstart, csr, xa, sv, M, 256, 0);
  int nmc = (M + 127) / 128;     // 391 M-chunks
  k_gemm<<<nmc * 4, 256, 0, stream>>>(xa, Wb, bias, sv, out, M);
}

// Round 20
// 206.204 us; speedup vs baseline: 2.0316x; 2.0316x over previous
//
#include <hip/hip_runtime.h>
#include <hip/hip_bf16.h>

#define K_DIM 512
#define N_DIM 512

typedef __attribute__((ext_vector_type(8))) short s8v;   // 8 bf16 bit-patterns (4 VGPR)
typedef __attribute__((ext_vector_type(4))) short s4v;
typedef __attribute__((ext_vector_type(4))) float f4v;

__device__ __forceinline__ short f2bf(float f) {
  union { float f; unsigned u; } v; v.f = f;
  unsigned r = (v.u + 0x7FFFu + ((v.u >> 16) & 1u)) >> 16;  // RNE
  return (short)r;
}
__device__ __forceinline__ float bflo(unsigned u) {
  union { unsigned u; float f; } v; v.u = u << 16; return v.f;
}
__device__ __forceinline__ float bfhi(unsigned u) {
  union { unsigned u; float f; } v; v.u = u & 0xffff0000u; return v.f;
}

// async global->LDS, 16B per lane. LDS dest = wave-uniform base (HW adds lane*16);
// global src is per-lane.
__device__ __forceinline__ void gload16(const void* g, void* l) {
  __builtin_amdgcn_global_load_lds(
      (const __attribute__((address_space(1))) void*)g,
      (__attribute__((address_space(3))) void*)l, 16, 0, 0);
}

// Per-wave inline int64-vs-int32 detection for edge_index (odd words all zero
// over the first 64 slots <=> int64 layout).
__device__ __forceinline__ int edge_stride(const int* __restrict__ e32, int lane) {
  int chk = e32[2 * lane + 1];
  unsigned long long m = __ballot(chk == 0);
  return (m == ~0ULL) ? 2 : 1;
}

// Plain histogram (probe-measured ~33us, atomic-chain-bound). Standalone so the
// streaming conv kernel doesn't contend with it (fusion cost ~20us, R19 probes).
__global__ __launch_bounds__(256) void k_hist(const int* __restrict__ e32,
    int* __restrict__ outdeg, int* __restrict__ indeg, int E) {
  int t = threadIdx.x;
  int st = edge_stride(e32, t & 63);
  int i = blockIdx.x * 256 + t;
  if (i < E) {
    int r = e32[(size_t)i * st];
    int c = e32[(size_t)(E + i) * st];
    atomicAdd(&outdeg[r], 1);
    atomicAdd(&indeg[c], 1);
  }
}

// Pure-streaming conversions: [0,nbw) convW | rest grid-stride ILP-4 convX.
__global__ __launch_bounds__(256) void k_convWX(const float* __restrict__ W,
    short* __restrict__ Wb, const float* __restrict__ x, short* __restrict__ xs,
    long long n4, int nbw, int nbx) {
  int b = blockIdx.x;
  int t = threadIdx.x;
  if (b < nbw) {
    int i = (b * 256 + t) * 4;
    float4 f = *(const float4*)(W + i);
    s4v s; s[0] = f2bf(f.x); s[1] = f2bf(f.y); s[2] = f2bf(f.z); s[3] = f2bf(f.w);
    *(s4v*)(Wb + i) = s;
  } else {
    const float4* x4 = (const float4*)x;
    s4v* xs4 = (s4v*)xs;
    long long i0 = (long long)(b - nbw) * 256 + t;
    const long long stride = (long long)nbx * 256;
    for (long long i = i0; i < n4; i += 4 * stride) {
      float4 f[4];
      #pragma unroll
      for (int u = 0; u < 4; ++u) {
        long long j = i + u * stride;
        f[u] = (j < n4) ? x4[j] : float4{0.f, 0.f, 0.f, 0.f};
      }
      #pragma unroll
      for (int u = 0; u < 4; ++u) {
        long long j = i + u * stride;
        if (j < n4) {
          s4v s;
          s[0] = f2bf(f[u].x); s[1] = f2bf(f[u].y);
          s[2] = f2bf(f[u].z); s[3] = f2bf(f[u].w);
          xs4[j] = s;
        }
      }
    }
  }
}

// Fused: [0,nbd) dis | [nbd,..) per-block partial sums of indeg.
__global__ __launch_bounds__(256) void k_pre2(const int* __restrict__ outdeg,
    float* __restrict__ dis, const int* __restrict__ indeg, int* __restrict__ part,
    int n, int nbd) {
  int b = blockIdx.x;
  if (b < nbd) {
    int i = b * 256 + threadIdx.x;
    if (i < n) dis[i] = rsqrtf((float)(outdeg[i] + 1));  // +1 self-loop
  } else {
    __shared__ int sm[256];
    int lb = b - nbd;
    int i = lb * 256 + threadIdx.x;
    sm[threadIdx.x] = (i < n) ? indeg[i] : 0;
    __syncthreads();
    for (int off = 128; off > 0; off >>= 1) {
      if (threadIdx.x < off) sm[threadIdx.x] += sm[threadIdx.x + off];
      __syncthreads();
    }
    if (threadIdx.x == 0) part[lb] = sm[0];
  }
}

// Self-contained scan: re-scan the <=256 PARTIALS in LDS, then local-scan slice.
__global__ __launch_bounds__(256) void k_scan(const int* __restrict__ indeg,
    const int* __restrict__ part, int* __restrict__ row_start,
    int* __restrict__ cursor, int n, int nb) {
  __shared__ int sp[256];
  __shared__ int sm[256];
  int t = threadIdx.x, b = blockIdx.x;
  sp[t] = (t < nb) ? part[t] : 0;
  __syncthreads();
  for (int off = 1; off < 256; off <<= 1) {
    int a = (t >= off) ? sp[t - off] : 0;
    __syncthreads();
    sp[t] += a;
    __syncthreads();
  }
  int pOff = (b > 0) ? sp[b - 1] : 0;
  if (b == 0 && t == 255) row_start[n] = sp[255];  // grand total (= E)
  int i = b * 256 + t;
  int v = (i < n) ? indeg[i] : 0;
  sm[t] = v;
  __syncthreads();
  for (int off = 1; off < 256; off <<= 1) {
    int a = (t >= off) ? sm[t - off] : 0;
    __syncthreads();
    sm[t] += a;
    __syncthreads();
  }
  if (i < n) {
    int excl = pOff + sm[t] - v;
    row_start[i] = excl;
    cursor[i] = excl;
  }
}

__global__ __launch_bounds__(256) void k_fill(const int* __restrict__ e32,
    int* __restrict__ cursor, int* __restrict__ csr, int E) {
  int st = edge_stride(e32, threadIdx.x & 63);
  int i = blockIdx.x * blockDim.x + threadIdx.x;
  if (i >= E) return;
  int r = e32[(size_t)i * st];
  int c = e32[(size_t)(E + i) * st];
  int p = atomicAdd(&cursor[c], 1);
  csr[p] = r;
}

__device__ __forceinline__ void fma4(float* acc, uint2 rv, float w) {
  acc[0] += w * bflo(rv.x); acc[1] += w * bfhi(rv.x);
  acc[2] += w * bflo(rv.y); acc[3] += w * bfhi(rv.y);
}

// Column-half aggregation pass: gathers only cols [coff, coff+256).
__global__ __launch_bounds__(256) void k_agg(const short* __restrict__ xs,
    const float* __restrict__ dis, const int* __restrict__ row_start,
    const int* __restrict__ csr, short* __restrict__ xa, float* __restrict__ s,
    int n, int coff, int writeS) {
  int wid = blockIdx.x * 4 + (threadIdx.x >> 6);
  int nw = gridDim.x * 4;
  int lane = threadIdx.x & 63;
  const short* hl = xs + coff + lane * 4;   // 8B per lane, 512B per row slice
  for (int v = wid; v < n; v += nw) {
    float dv = dis[v];
    float acc[4];
    float accs = dv;
    {
      uint2 r = *(const uint2*)(hl + (size_t)v * N_DIM);  // self-loop (w = dv)
      acc[0] = dv * bflo(r.x); acc[1] = dv * bfhi(r.x);
      acc[2] = dv * bflo(r.y); acc[3] = dv * bfhi(r.y);
    }
    int sb = __builtin_amdgcn_readfirstlane(row_start[v]);
    int eb = __builtin_amdgcn_readfirstlane(row_start[v + 1]);
    int idx = sb;
    for (; idx + 8 <= eb; idx += 8) {
      int s0 = csr[idx],     s1 = csr[idx + 1], s2 = csr[idx + 2], s3 = csr[idx + 3];
      int s4 = csr[idx + 4], s5 = csr[idx + 5], s6 = csr[idx + 6], s7 = csr[idx + 7];
      float w0 = dis[s0], w1 = dis[s1], w2 = dis[s2], w3 = dis[s3];
      float w4 = dis[s4], w5 = dis[s5], w6 = dis[s6], w7 = dis[s7];
      uint2 r0 = *(const uint2*)(hl + (size_t)s0 * N_DIM);
      uint2 r1 = *(const uint2*)(hl + (size_t)s1 * N_DIM);
      uint2 r2 = *(const uint2*)(hl + (size_t)s2 * N_DIM);
      uint2 r3 = *(const uint2*)(hl + (size_t)s3 * N_DIM);
      uint2 r4 = *(const uint2*)(hl + (size_t)s4 * N_DIM);
      uint2 r5 = *(const uint2*)(hl + (size_t)s5 * N_DIM);
      uint2 r6 = *(const uint2*)(hl + (size_t)s6 * N_DIM);
      uint2 r7 = *(const uint2*)(hl + (size_t)s7 * N_DIM);
      accs += w0 + w1 + w2 + w3 + w4 + w5 + w6 + w7;
      fma4(acc, r0, w0); fma4(acc, r1, w1); fma4(acc, r2, w2); fma4(acc, r3, w3);
      fma4(acc, r4, w4); fma4(acc, r5, w5); fma4(acc, r6, w6); fma4(acc, r7, w7);
    }
    for (; idx + 4 <= eb; idx += 4) {
      int s0 = csr[idx], s1 = csr[idx + 1], s2 = csr[idx + 2], s3 = csr[idx + 3];
      float w0 = dis[s0], w1 = dis[s1], w2 = dis[s2], w3 = dis[s3];
      uint2 r0 = *(const uint2*)(hl + (size_t)s0 * N_DIM);
      uint2 r1 = *(const uint2*)(hl + (size_t)s1 * N_DIM);
      uint2 r2 = *(const uint2*)(hl + (size_t)s2 * N_DIM);
      uint2 r3 = *(const uint2*)(hl + (size_t)s3 * N_DIM);
      accs += w0 + w1 + w2 + w3;
      fma4(acc, r0, w0); fma4(acc, r1, w1); fma4(acc, r2, w2); fma4(acc, r3, w3);
    }
    for (; idx < eb; ++idx) {
      int s0 = csr[idx];
      float w0 = dis[s0];
      uint2 r0 = *(const uint2*)(hl + (size_t)s0 * N_DIM);
      accs += w0;
      fma4(acc, r0, w0);
    }
    s4v o;
    o[0] = f2bf(dv * acc[0]); o[1] = f2bf(dv * acc[1]);
    o[2] = f2bf(dv * acc[2]); o[3] = f2bf(dv * acc[3]);
    *(s4v*)(xa + (size_t)v * N_DIM + coff + lane * 4) = o;
    if (writeS && lane == 0) s[v] = dv * accs;
  }
}

// out[M][512] (f32) = relu( xa[M][512](bf16) @ Wb^T + s[row]*bias )
// R10-proven: m97-lean 2-phase K-loop + LDS-transpose epilogue.
__global__ __launch_bounds__(256, 4) void k_gemm(const short* __restrict__ xa,
    const short* __restrict__ Wb, const float* __restrict__ bias,
    const float* __restrict__ s, float* __restrict__ out, int M) {
  __shared__ __align__(16) char smem[32768];
  short* As = (short*)smem;             // [2][128*32] shorts = 16KB
  short* Bs = (short*)(smem + 16384);   // 16KB
  // --- XCD-chunked bijective swizzle (8 XCDs, m204) ---
  int nwg = gridDim.x;
  int orig = blockIdx.x;
  int q8 = nwg >> 3, r8 = nwg & 7;
  int xcd = orig & 7, pos = orig >> 3;
  int swz = (xcd < r8 ? xcd * (q8 + 1) : r8 * (q8 + 1) + (xcd - r8) * q8) + pos;
  const int n0 = (swz & 3) * 128;    // N fastest within swz chunk
  const int m0 = (swz >> 2) * 128;

  const int tid = threadIdx.x;
  const int lane = tid & 63;
  const int wv = tid >> 6, wr = wv >> 1, wc = wv & 1;
  const int la = lane & 15, lg = lane >> 4;

  // staging: 2 rounds x 256 lanes x 16B cover 128 rows x 64B (BK=32 bf16)
  const short* ag[2];
  const short* bg[2];
  int doff[2];
  #pragma unroll
  for (int r = 0; r < 2; ++r) {
    int id = r * 256 + tid;
    int row = id >> 2;               // 0..127
    int ch = id & 3;                 // 16B chunk within row
    int arow = m0 + row; if (arow >= M) arow = M - 1;  // clamp: no OOB
    ag[r] = xa + (size_t)arow * K_DIM + ch * 8;
    bg[r] = Wb + (size_t)(n0 + row) * K_DIM + ch * 8;
    doff[r] = (r * 256 + (tid & 192)) * 16;  // wave-uniform byte base
  }
  // fragment read offsets
  int aro[4], bro[4];
  #pragma unroll
  for (int i = 0; i < 4; ++i) {
    aro[i] = (64 * wr + 16 * i + la) * 64 + lg * 16;
    bro[i] = (64 * wc + 16 * i + la) * 64 + lg * 16;
  }

  f4v acc[4][4] = {};

  // prologue: k-tile 0 -> buffer 0
  #pragma unroll
  for (int r = 0; r < 2; ++r) {
    gload16(ag[r], (char*)As + doff[r]);
    gload16(bg[r], (char*)Bs + doff[r]);
  }
  __syncthreads();

  for (int kt = 0; kt < 16; ++kt) {
    const int cur = kt & 1;
    const int nxt = cur ^ 1;
    if (kt < 15) {
      const int kk = (kt + 1) * 32;
      #pragma unroll
      for (int r = 0; r < 2; ++r) {
        gload16(ag[r] + kk, (char*)As + nxt * 8192 + doff[r]);
        gload16(bg[r] + kk, (char*)Bs + nxt * 8192 + doff[r]);
      }
    }
    s8v af[4], bf[4];
    const char* ab = (const char*)As + cur * 8192;
    const char* bb = (const char*)Bs + cur * 8192;
    #pragma unroll
    for (int i = 0; i < 4; ++i) af[i] = *(const s8v*)(ab + aro[i]);
    #pragma unroll
    for (int j = 0; j < 4; ++j) bf[j] = *(const s8v*)(bb + bro[j]);
    #pragma unroll
    for (int i = 0; i < 4; ++i)
      #pragma unroll
      for (int j = 0; j < 4; ++j)
        acc[i][j] = __builtin_amdgcn_mfma_f32_16x16x32_bf16(af[i], bf[j], acc[i][j], 0, 0, 0);
    __syncthreads();  // drains vmcnt/lgkm: nxt staged, cur reads done
  }

  // epilogue: per 16-row slice, transpose through per-wave LDS region.
  float* Es = (float*)(smem + wv * 4352);
  float bv[4];
  #pragma unroll
  for (int j = 0; j < 4; ++j) bv[j] = bias[n0 + 64 * wc + 16 * j + la];
  #pragma unroll
  for (int i = 0; i < 4; ++i) {
    int rowb = m0 + 64 * wr + 16 * i + lg * 4;
    float sv[4];
    #pragma unroll
    for (int r = 0; r < 4; ++r) sv[r] = (rowb + r < M) ? s[rowb + r] : 0.f;
    #pragma unroll
    for (int j = 0; j < 4; ++j)
      #pragma unroll
      for (int r = 0; r < 4; ++r)
        Es[(lg * 4 + r) * 68 + 16 * j + la] = fmaxf(acc[i][j][r] + sv[r] * bv[j], 0.f);
    asm volatile("s_waitcnt lgkmcnt(0)" ::: "memory");  // ds_writes visible
    int gr0 = m0 + 64 * wr + 16 * i;
    #pragma unroll
    for (int rr = 0; rr < 4; ++rr) {
      int id = rr * 64 + lane;
      int rl = id >> 4, ch = id & 15;
      f4v val = *(const f4v*)&Es[rl * 68 + ch * 4];
      if (gr0 + rl < M)
        __builtin_nontemporal_store(val,
            (f4v*)(out + (size_t)(gr0 + rl) * N_DIM + n0 + 64 * wc + ch * 4));
    }
    asm volatile("s_waitcnt lgkmcnt(0)" ::: "memory");  // reads done before next i
  }
}

extern "C" void kernel_launch(void* const* d_in, const int* in_sizes, int n_in,
                              void* d_out, int out_size, void* d_ws, size_t ws_size,
                              hipStream_t stream) {
  const float* x = (const float*)d_in[0];
  const int* e32 = (const int*)d_in[1];
  const float* W = (const float*)d_in[2];
  const float* bias = (const float*)d_in[3];
  float* out = (float*)d_out;
  int M = in_sizes[0] / K_DIM;   // 50000
  int E = in_sizes[1] / 2;       // 400000

  char* ws = (char*)d_ws;
  size_t off = 0;
  auto alloc = [&](size_t bytes) {
    void* p = ws + off;
    off = (off + bytes + 255) & ~(size_t)255;
    return p;
  };
  short* Wb      = (short*)alloc((size_t)N_DIM * K_DIM * 2);
  short* xa      = (short*)alloc((size_t)M * N_DIM * 2);   // aggregated bf16 features
  float* dis     = (float*)alloc((size_t)M * 4);
  float* sv      = (float*)alloc((size_t)M * 4);           // s[v] bias scale
  int*   outdeg  = (int*)alloc((size_t)M * 4);
  int*   indeg   = (int*)alloc((size_t)M * 4);             // contiguous after outdeg
  int*   rstart  = (int*)alloc((size_t)(M + 1) * 4);
  int*   cursor  = (int*)alloc((size_t)M * 4);
  int*   part    = (int*)alloc(256 * 4);
  int*   csr     = (int*)alloc((size_t)E * 4);
  if (off > ws_size) return;  // workspace too small: fail loudly via absmax

  // xs (plain bf16 x) lives in d_out scratch: dead before k_gemm writes out.
  short* xs = (short*)d_out;   // 51.2MB <= out's 102.4MB

  // one memset covers outdeg..indeg (contiguous in ws)
  size_t zbytes = (size_t)((char*)indeg - (char*)outdeg) + (size_t)M * 4;
  (void)hipMemsetAsync(outdeg, 0, zbytes, stream);

  long long n4 = (long long)M * K_DIM / 4;            // 6.4M float4s
  int nbw = N_DIM * K_DIM / 4 / 256;                  // 256
  int nbx = 2048;                                     // grid-stride convX blocks
  int nbh = (E + 255) / 256;                          // 1563
  k_hist<<<nbh, 256, 0, stream>>>(e32, outdeg, indeg, E);
  k_convWX<<<nbw + nbx, 256, 0, stream>>>(W, Wb, x, xs, n4, nbw, nbx);
  int nscan = (M + 255) / 256;  // 196 (must be <= 256)
  k_pre2<<<nscan * 2, 256, 0, stream>>>(outdeg, dis, indeg, part, M, nscan);
  k_scan<<<nscan, 256, 0, stream>>>(indeg, part, rstart, cursor, M, nscan);
  k_fill<<<nbh, 256, 0, stream>>>(e32, cursor, csr, E);
  k_agg<<<2048, 256, 0, stream>>>(xs, dis, rstart, csr, xa, sv, M, 0, 1);
  k_agg<<<2048, 256, 0, stream>>>(xs, dis, rstart, csr, xa, sv, M, 256, 0);
  int nmc = (M + 127) / 128;     // 391 M-chunks
  k_gemm<<<nmc * 4, 256, 0, stream>>>(xa, Wb, bias, sv, out, M);
}

// Round 21
// 198.566 us; speedup vs baseline: 2.1097x; 1.0385x over previous
//
#include <hip/hip_runtime.h>
#include <hip/hip_bf16.h>

#define K_DIM 512
#define N_DIM 512

typedef __attribute__((ext_vector_type(8))) short s8v;   // 8 bf16 bit-patterns (4 VGPR)
typedef __attribute__((ext_vector_type(4))) short s4v;
typedef __attribute__((ext_vector_type(4))) float f4v;

__device__ __forceinline__ short f2bf(float f) {
  union { float f; unsigned u; } v; v.f = f;
  unsigned r = (v.u + 0x7FFFu + ((v.u >> 16) & 1u)) >> 16;  // RNE
  return (short)r;
}
__device__ __forceinline__ float bflo(unsigned u) {
  union { unsigned u; float f; } v; v.u = u << 16; return v.f;
}
__device__ __forceinline__ float bfhi(unsigned u) {
  union { unsigned u; float f; } v; v.u = u & 0xffff0000u; return v.f;
}

// async global->LDS, 16B per lane. LDS dest = wave-uniform base (HW adds lane*16);
// global src is per-lane.
__device__ __forceinline__ void gload16(const void* g, void* l) {
  __builtin_amdgcn_global_load_lds(
      (const __attribute__((address_space(1))) void*)g,
      (__attribute__((address_space(3))) void*)l, 16, 0, 0);
}

// Per-wave inline int64-vs-int32 detection for edge_index (odd words all zero
// over the first 64 slots <=> int64 layout).
__device__ __forceinline__ int edge_stride(const int* __restrict__ e32, int lane) {
  int chk = e32[2 * lane + 1];
  unsigned long long m = __ballot(chk == 0);
  return (m == ~0ULL) ? 2 : 1;
}

// Fused prep: [0,nbw) convW | [nbw,nbw+nbx) convX grid-stride ILP-4 | rest hist.
// (R16 configuration: measured optimum of all conv/hist arrangements.)
__global__ __launch_bounds__(256) void k_pre1(const float* __restrict__ W,
    short* __restrict__ Wb, const float* __restrict__ x, short* __restrict__ xs,
    long long n4, const int* __restrict__ e32,
    int* __restrict__ outdeg, int* __restrict__ indeg, int E, int nbw, int nbx) {
  int b = blockIdx.x;
  int t = threadIdx.x;
  if (b < nbw) {
    int i = (b * 256 + t) * 4;
    float4 f = *(const float4*)(W + i);
    s4v s; s[0] = f2bf(f.x); s[1] = f2bf(f.y); s[2] = f2bf(f.z); s[3] = f2bf(f.w);
    *(s4v*)(Wb + i) = s;
  } else if (b < nbw + nbx) {
    const float4* x4 = (const float4*)x;
    s4v* xs4 = (s4v*)xs;
    long long i0 = (long long)(b - nbw) * 256 + t;
    const long long stride = (long long)nbx * 256;
    for (long long i = i0; i < n4; i += 4 * stride) {
      float4 f[4];
      #pragma unroll
      for (int u = 0; u < 4; ++u) {
        long long j = i + u * stride;
        f[u] = (j < n4) ? x4[j] : float4{0.f, 0.f, 0.f, 0.f};
      }
      #pragma unroll
      for (int u = 0; u < 4; ++u) {
        long long j = i + u * stride;
        if (j < n4) {
          s4v s;
          s[0] = f2bf(f[u].x); s[1] = f2bf(f[u].y);
          s[2] = f2bf(f[u].z); s[3] = f2bf(f[u].w);
          xs4[j] = s;
        }
      }
    }
  } else {
    int st = edge_stride(e32, t & 63);
    int i = (b - nbw - nbx) * 256 + t;
    if (i < E) {
      int r = e32[(size_t)i * st];
      int c = e32[(size_t)(E + i) * st];
      atomicAdd(&outdeg[r], 1);
      atomicAdd(&indeg[c], 1);
    }
  }
}

// Fused: [0,nbd) dis | [nbd,..) per-block partial sums of indeg.
__global__ __launch_bounds__(256) void k_pre2(const int* __restrict__ outdeg,
    float* __restrict__ dis, const int* __restrict__ indeg, int* __restrict__ part,
    int n, int nbd) {
  int b = blockIdx.x;
  if (b < nbd) {
    int i = b * 256 + threadIdx.x;
    if (i < n) dis[i] = rsqrtf((float)(outdeg[i] + 1));  // +1 self-loop
  } else {
    __shared__ int sm[256];
    int lb = b - nbd;
    int i = lb * 256 + threadIdx.x;
    sm[threadIdx.x] = (i < n) ? indeg[i] : 0;
    __syncthreads();
    for (int off = 128; off > 0; off >>= 1) {
      if (threadIdx.x < off) sm[threadIdx.x] += sm[threadIdx.x + off];
      __syncthreads();
    }
    if (threadIdx.x == 0) part[lb] = sm[0];
  }
}

// Self-contained scan: re-scan the <=256 PARTIALS in LDS, then local-scan slice.
__global__ __launch_bounds__(256) void k_scan(const int* __restrict__ indeg,
    const int* __restrict__ part, int* __restrict__ row_start,
    int* __restrict__ cursor, int n, int nb) {
  __shared__ int sp[256];
  __shared__ int sm[256];
  int t = threadIdx.x, b = blockIdx.x;
  sp[t] = (t < nb) ? part[t] : 0;
  __syncthreads();
  for (int off = 1; off < 256; off <<= 1) {
    int a = (t >= off) ? sp[t - off] : 0;
    __syncthreads();
    sp[t] += a;
    __syncthreads();
  }
  int pOff = (b > 0) ? sp[b - 1] : 0;
  if (b == 0 && t == 255) row_start[n] = sp[255];  // grand total (= E)
  int i = b * 256 + t;
  int v = (i < n) ? indeg[i] : 0;
  sm[t] = v;
  __syncthreads();
  for (int off = 1; off < 256; off <<= 1) {
    int a = (t >= off) ? sm[t - off] : 0;
    __syncthreads();
    sm[t] += a;
    __syncthreads();
  }
  if (i < n) {
    int excl = pOff + sm[t] - v;
    row_start[i] = excl;
    cursor[i] = excl;
  }
}

__global__ __launch_bounds__(256) void k_fill(const int* __restrict__ e32,
    int* __restrict__ cursor, int* __restrict__ csr, int E) {
  int st = edge_stride(e32, threadIdx.x & 63);
  int i = blockIdx.x * blockDim.x + threadIdx.x;
  if (i >= E) return;
  int r = e32[(size_t)i * st];
  int c = e32[(size_t)(E + i) * st];
  int p = atomicAdd(&cursor[c], 1);
  csr[p] = r;
}

__device__ __forceinline__ void fma4(float* acc, uint2 rv, float w) {
  acc[0] += w * bflo(rv.x); acc[1] += w * bfhi(rv.x);
  acc[2] += w * bflo(rv.y); acc[3] += w * bfhi(rv.y);
}

// Column-half aggregation pass: gathers only cols [coff, coff+256).
__global__ __launch_bounds__(256) void k_agg(const short* __restrict__ xs,
    const float* __restrict__ dis, const int* __restrict__ row_start,
    const int* __restrict__ csr, short* __restrict__ xa, float* __restrict__ s,
    int n, int coff, int writeS) {
  int wid = blockIdx.x * 4 + (threadIdx.x >> 6);
  int nw = gridDim.x * 4;
  int lane = threadIdx.x & 63;
  const short* hl = xs + coff + lane * 4;   // 8B per lane, 512B per row slice
  for (int v = wid; v < n; v += nw) {
    float dv = dis[v];
    float acc[4];
    float accs = dv;
    {
      uint2 r = *(const uint2*)(hl + (size_t)v * N_DIM);  // self-loop (w = dv)
      acc[0] = dv * bflo(r.x); acc[1] = dv * bfhi(r.x);
      acc[2] = dv * bflo(r.y); acc[3] = dv * bfhi(r.y);
    }
    int sb = __builtin_amdgcn_readfirstlane(row_start[v]);
    int eb = __builtin_amdgcn_readfirstlane(row_start[v + 1]);
    int idx = sb;
    for (; idx + 8 <= eb; idx += 8) {
      int s0 = csr[idx],     s1 = csr[idx + 1], s2 = csr[idx + 2], s3 = csr[idx + 3];
      int s4 = csr[idx + 4], s5 = csr[idx + 5], s6 = csr[idx + 6], s7 = csr[idx + 7];
      float w0 = dis[s0], w1 = dis[s1], w2 = dis[s2], w3 = dis[s3];
      float w4 = dis[s4], w5 = dis[s5], w6 = dis[s6], w7 = dis[s7];
      uint2 r0 = *(const uint2*)(hl + (size_t)s0 * N_DIM);
      uint2 r1 = *(const uint2*)(hl + (size_t)s1 * N_DIM);
      uint2 r2 = *(const uint2*)(hl + (size_t)s2 * N_DIM);
      uint2 r3 = *(const uint2*)(hl + (size_t)s3 * N_DIM);
      uint2 r4 = *(const uint2*)(hl + (size_t)s4 * N_DIM);
      uint2 r5 = *(const uint2*)(hl + (size_t)s5 * N_DIM);
      uint2 r6 = *(const uint2*)(hl + (size_t)s6 * N_DIM);
      uint2 r7 = *(const uint2*)(hl + (size_t)s7 * N_DIM);
      accs += w0 + w1 + w2 + w3 + w4 + w5 + w6 + w7;
      fma4(acc, r0, w0); fma4(acc, r1, w1); fma4(acc, r2, w2); fma4(acc, r3, w3);
      fma4(acc, r4, w4); fma4(acc, r5, w5); fma4(acc, r6, w6); fma4(acc, r7, w7);
    }
    for (; idx + 4 <= eb; idx += 4) {
      int s0 = csr[idx], s1 = csr[idx + 1], s2 = csr[idx + 2], s3 = csr[idx + 3];
      float w0 = dis[s0], w1 = dis[s1], w2 = dis[s2], w3 = dis[s3];
      uint2 r0 = *(const uint2*)(hl + (size_t)s0 * N_DIM);
      uint2 r1 = *(const uint2*)(hl + (size_t)s1 * N_DIM);
      uint2 r2 = *(const uint2*)(hl + (size_t)s2 * N_DIM);
      uint2 r3 = *(const uint2*)(hl + (size_t)s3 * N_DIM);
      accs += w0 + w1 + w2 + w3;
      fma4(acc, r0, w0); fma4(acc, r1, w1); fma4(acc, r2, w2); fma4(acc, r3, w3);
    }
    for (; idx < eb; ++idx) {
      int s0 = csr[idx];
      float w0 = dis[s0];
      uint2 r0 = *(const uint2*)(hl + (size_t)s0 * N_DIM);
      accs += w0;
      fma4(acc, r0, w0);
    }
    s4v o;
    o[0] = f2bf(dv * acc[0]); o[1] = f2bf(dv * acc[1]);
    o[2] = f2bf(dv * acc[2]); o[3] = f2bf(dv * acc[3]);
    *(s4v*)(xa + (size_t)v * N_DIM + coff + lane * 4) = o;
    if (writeS && lane == 0) s[v] = dv * accs;
  }
}

// out[M][512] (f32) = relu( xa[M][512](bf16) @ Wb^T + s[row]*bias )
// R10-proven: m97-lean 2-phase K-loop + LDS-transpose epilogue.
__global__ __launch_bounds__(256, 4) void k_gemm(const short* __restrict__ xa,
    const short* __restrict__ Wb, const float* __restrict__ bias,
    const float* __restrict__ s, float* __restrict__ out, int M) {
  __shared__ __align__(16) char smem[32768];
  short* As = (short*)smem;             // [2][128*32] shorts = 16KB
  short* Bs = (short*)(smem + 16384);   // 16KB
  // --- XCD-chunked bijective swizzle (8 XCDs, m204) ---
  int nwg = gridDim.x;
  int orig = blockIdx.x;
  int q8 = nwg >> 3, r8 = nwg & 7;
  int xcd = orig & 7, pos = orig >> 3;
  int swz = (xcd < r8 ? xcd * (q8 + 1) : r8 * (q8 + 1) + (xcd - r8) * q8) + pos;
  const int n0 = (swz & 3) * 128;    // N fastest within swz chunk
  const int m0 = (swz >> 2) * 128;

  const int tid = threadIdx.x;
  const int lane = tid & 63;
  const int wv = tid >> 6, wr = wv >> 1, wc = wv & 1;
  const int la = lane & 15, lg = lane >> 4;

  // staging: 2 rounds x 256 lanes x 16B cover 128 rows x 64B (BK=32 bf16)
  const short* ag[2];
  const short* bg[2];
  int doff[2];
  #pragma unroll
  for (int r = 0; r < 2; ++r) {
    int id = r * 256 + tid;
    int row = id >> 2;               // 0..127
    int ch = id & 3;                 // 16B chunk within row
    int arow = m0 + row; if (arow >= M) arow = M - 1;  // clamp: no OOB
    ag[r] = xa + (size_t)arow * K_DIM + ch * 8;
    bg[r] = Wb + (size_t)(n0 + row) * K_DIM + ch * 8;
    doff[r] = (r * 256 + (tid & 192)) * 16;  // wave-uniform byte base
  }
  // fragment read offsets
  int aro[4], bro[4];
  #pragma unroll
  for (int i = 0; i < 4; ++i) {
    aro[i] = (64 * wr + 16 * i + la) * 64 + lg * 16;
    bro[i] = (64 * wc + 16 * i + la) * 64 + lg * 16;
  }

  f4v acc[4][4] = {};

  // prologue: k-tile 0 -> buffer 0
  #pragma unroll
  for (int r = 0; r < 2; ++r) {
    gload16(ag[r], (char*)As + doff[r]);
    gload16(bg[r], (char*)Bs + doff[r]);
  }
  __syncthreads();

  for (int kt = 0; kt < 16; ++kt) {
    const int cur = kt & 1;
    const int nxt = cur ^ 1;
    if (kt < 15) {
      const int kk = (kt + 1) * 32;
      #pragma unroll
      for (int r = 0; r < 2; ++r) {
        gload16(ag[r] + kk, (char*)As + nxt * 8192 + doff[r]);
        gload16(bg[r] + kk, (char*)Bs + nxt * 8192 + doff[r]);
      }
    }
    s8v af[4], bf[4];
    const char* ab = (const char*)As + cur * 8192;
    const char* bb = (const char*)Bs + cur * 8192;
    #pragma unroll
    for (int i = 0; i < 4; ++i) af[i] = *(const s8v*)(ab + aro[i]);
    #pragma unroll
    for (int j = 0; j < 4; ++j) bf[j] = *(const s8v*)(bb + bro[j]);
    #pragma unroll
    for (int i = 0; i < 4; ++i)
      #pragma unroll
      for (int j = 0; j < 4; ++j)
        acc[i][j] = __builtin_amdgcn_mfma_f32_16x16x32_bf16(af[i], bf[j], acc[i][j], 0, 0, 0);
    __syncthreads();  // drains vmcnt/lgkm: nxt staged, cur reads done
  }

  // epilogue: per 16-row slice, transpose through per-wave LDS region.
  float* Es = (float*)(smem + wv * 4352);
  float bv[4];
  #pragma unroll
  for (int j = 0; j < 4; ++j) bv[j] = bias[n0 + 64 * wc + 16 * j + la];
  #pragma unroll
  for (int i = 0; i < 4; ++i) {
    int rowb = m0 + 64 * wr + 16 * i + lg * 4;
    float sv[4];
    #pragma unroll
    for (int r = 0; r < 4; ++r) sv[r] = (rowb + r < M) ? s[rowb + r] : 0.f;
    #pragma unroll
    for (int j = 0; j < 4; ++j)
      #pragma unroll
      for (int r = 0; r < 4; ++r)
        Es[(lg * 4 + r) * 68 + 16 * j + la] = fmaxf(acc[i][j][r] + sv[r] * bv[j], 0.f);
    asm volatile("s_waitcnt lgkmcnt(0)" ::: "memory");  // ds_writes visible
    int gr0 = m0 + 64 * wr + 16 * i;
    #pragma unroll
    for (int rr = 0; rr < 4; ++rr) {
      int id = rr * 64 + lane;
      int rl = id >> 4, ch = id & 15;
      f4v val = *(const f4v*)&Es[rl * 68 + ch * 4];
      if (gr0 + rl < M)
        __builtin_nontemporal_store(val,
            (f4v*)(out + (size_t)(gr0 + rl) * N_DIM + n0 + 64 * wc + ch * 4));
    }
    asm volatile("s_waitcnt lgkmcnt(0)" ::: "memory");  // reads done before next i
  }
}

extern "C" void kernel_launch(void* const* d_in, const int* in_sizes, int n_in,
                              void* d_out, int out_size, void* d_ws, size_t ws_size,
                              hipStream_t stream) {
  const float* x = (const float*)d_in[0];
  const int* e32 = (const int*)d_in[1];
  const float* W = (const float*)d_in[2];
  const float* bias = (const float*)d_in[3];
  float* out = (float*)d_out;
  int M = in_sizes[0] / K_DIM;   // 50000
  int E = in_sizes[1] / 2;       // 400000

  char* ws = (char*)d_ws;
  size_t off = 0;
  auto alloc = [&](size_t bytes) {
    void* p = ws + off;
    off = (off + bytes + 255) & ~(size_t)255;
    return p;
  };
  short* Wb      = (short*)alloc((size_t)N_DIM * K_DIM * 2);
  short* xa      = (short*)alloc((size_t)M * N_DIM * 2);   // aggregated bf16 features
  float* dis     = (float*)alloc((size_t)M * 4);
  float* sv      = (float*)alloc((size_t)M * 4);           // s[v] bias scale
  int*   outdeg  = (int*)alloc((size_t)M * 4);
  int*   indeg   = (int*)alloc((size_t)M * 4);             // contiguous after outdeg
  int*   rstart  = (int*)alloc((size_t)(M + 1) * 4);
  int*   cursor  = (int*)alloc((size_t)M * 4);
  int*   part    = (int*)alloc(256 * 4);
  int*   csr     = (int*)alloc((size_t)E * 4);
  if (off > ws_size) return;  // workspace too small: fail loudly via absmax

  // xs (plain bf16 x) lives in d_out scratch: dead before k_gemm writes out.
  short* xs = (short*)d_out;   // 51.2MB <= out's 102.4MB

  // one memset covers outdeg..indeg (contiguous in ws)
  size_t zbytes = (size_t)((char*)indeg - (char*)outdeg) + (size_t)M * 4;
  (void)hipMemsetAsync(outdeg, 0, zbytes, stream);

  long long n4 = (long long)M * K_DIM / 4;            // 6.4M float4s
  int nbw = N_DIM * K_DIM / 4 / 256;                  // 256
  int nbx = 2048;                                     // grid-stride convX blocks
  int nbh = (E + 255) / 256;                          // 1563
  k_pre1<<<nbw + nbx + nbh, 256, 0, stream>>>(W, Wb, x, xs, n4, e32,
                                              outdeg, indeg, E, nbw, nbx);
  int nscan = (M + 255) / 256;  // 196 (must be <= 256)
  k_pre2<<<nscan * 2, 256, 0, stream>>>(outdeg, dis, indeg, part, M, nscan);
  k_scan<<<nscan, 256, 0, stream>>>(indeg, part, rstart, cursor, M, nscan);
  k_fill<<<nbh, 256, 0, stream>>>(e32, cursor, csr, E);
  k_agg<<<2048, 256, 0, stream>>>(xs, dis, rstart, csr, xa, sv, M, 0, 1);
  k_agg<<<2048, 256, 0, stream>>>(xs, dis, rstart, csr, xa, sv, M, 256, 0);
  int nmc = (M + 127) / 128;     // 391 M-chunks
  k_gemm<<<nmc * 4, 256, 0, stream>>>(xa, Wb, bias, sv, out, M);
}